// Round 10
// baseline (172.016 us; speedup 1.0000x reference)
//
#include <hip/hip_runtime.h>
#include <hip/hip_fp16.h>
#include <hip/hip_cooperative_groups.h>

namespace cg = cooperative_groups;

#define NGRID 64
#define NEL (NGRID*NGRID*NGRID)   /* 262144 */
#define IDX(i,j,k) ((((i)*64 + (j)) * 64) + (k))

#define NSLAB    16                /* slab = 4 consecutive i-planes = 16384 elements */
#define SLAB_EL  16384
#define NTYPE    256
#define SLAB_PAD 32768             /* per-slab sorted region (worst-case 64-padding) */
#define PADTOT   (NSLAB*SLAB_PAD)  /* 524288 */
#define NSLOT    (PADTOT/64)       /* 8192 slot-table entries */
#define SLAB_SLOTS (SLAB_PAD/64)   /* 512 */

// ---- workspace layout (bytes) ----
#define WS_U4     0                                   // NEL float4 = 4 MB
#define WS_KUE    (WS_U4 + (size_t)NEL*16)            // NEL*64 B  = 16 MB (fp16, 1 line/elem)
#define WS_SORTED (WS_KUE + (size_t)NEL*64)           // PADTOT i32 = 2 MB
#define WS_TYPES  (WS_SORTED + (size_t)PADTOT*4)      // NEL u8 = 256 KB
#define WS_BHIST  (WS_TYPES + NEL)                    // 4096*16 i32 ([slab][type][inner16])
#define WS_SLOT   (WS_BHIST + 4096*16*4)              // NSLOT i32 = 32 KB
#define WS_NEEDED (size_t)(WS_SLOT + NSLOT*4)

__device__ __forceinline__ int type_of(const float* __restrict__ rho, int i, int j, int k) {
    int i1 = (i + 1) & 63, j1 = (j + 1) & 63, k1 = (k + 1) & 63;
    // typeFilter[di][dj][dk] = 2^(di*4 + dj*2 + dk); OFFSETS order -> bits {0,4,2,6,1,5,3,7}
    int t = 0;
    t |= (rho[IDX(i,  j,  k )] > 0.5f ? 1 : 0) << 0;
    t |= (rho[IDX(i1, j,  k )] > 0.5f ? 1 : 0) << 4;
    t |= (rho[IDX(i,  j1, k )] > 0.5f ? 1 : 0) << 2;
    t |= (rho[IDX(i1, j1, k )] > 0.5f ? 1 : 0) << 6;
    t |= (rho[IDX(i,  j,  k1)] > 0.5f ? 1 : 0) << 1;
    t |= (rho[IDX(i1, j,  k1)] > 0.5f ? 1 : 0) << 5;
    t |= (rho[IDX(i,  j1, k1)] > 0.5f ? 1 : 0) << 3;
    t |= (rho[IDX(i1, j1, k1)] > 0.5f ? 1 : 0) << 7;
    return t;
}

// ======================= fused cooperative kernel =======================
// 256 blocks x 1024 threads, 1 block/CU (launch_bounds caps VGPR at 128).
// Phases P1..P5 = old k1..k5; grid.sync() replaces kernel boundaries.
// XCD-pinning invariant: slab s is touched only by blocks b with b%8 == s%8
// in every phase, so U4/KUe slab regions stay in one XCD's L2.
__global__ __launch_bounds__(1024, 4) void fe_fused(
    const float* __restrict__ U, const float* __restrict__ rho,
    const float* __restrict__ filters,
    float4* __restrict__ U4, unsigned char* __restrict__ types,
    int* __restrict__ bhist, int* __restrict__ slotinfo,
    int* __restrict__ sorted, float4* __restrict__ KUe16,
    float* __restrict__ out)
{
    cg::grid_group grid = cg::this_grid();
    __shared__ int lh[NTYPE];
    __shared__ int s[NTYPE];
    __shared__ int used;
    int tid = threadIdx.x;
    int b = blockIdx.x;

    // ---- P1: pack U->float4, types, per-(slab,type,inner) LDS hist ----
    {
        int slab = b & 15, inner = b >> 4;
        if (tid < NTYPE) lh[tid] = 0;
        __syncthreads();
        int e = slab * SLAB_EL + inner * 1024 + tid;
        U4[e] = make_float4(U[3*e + 0], U[3*e + 1], U[3*e + 2], 0.0f);
        int k = e & 63, j = (e >> 6) & 63, i = (e >> 12) & 63;
        int t = type_of(rho, i, j, k);
        types[e] = (unsigned char)t;
        atomicAdd(&lh[t], 1);                 // LDS-only atomic
        __syncthreads();
        if (tid < NTYPE) bhist[(slab * NTYPE + tid) * 16 + inner] = lh[tid];
    }
    grid.sync();

    // ---- P2: per-slab scan + slot table (blocks 0..15 only) ----
    if (b < NSLAB) {
        int slab = b;
        int c[16], sum = 0, padded = 0;
        if (tid < NTYPE) {
            int base = (slab * NTYPE + tid) * 16;
            #pragma unroll
            for (int in = 0; in < 16; ++in) { c[in] = bhist[base + in]; sum += c[in]; }
            padded = (sum + 63) & ~63;
            s[tid] = padded;
        }
        __syncthreads();
        #pragma unroll
        for (int off = 1; off < 256; off <<= 1) {
            int tmp = (tid < NTYPE && tid >= off) ? s[tid - off] : 0;
            __syncthreads();
            if (tid < NTYPE) s[tid] += tmp;
            __syncthreads();
        }
        if (tid < NTYPE) {
            int excl = s[tid] - padded;                 // exclusive scan, mult of 64
            int run = slab * SLAB_PAD + excl;
            int base = (slab * NTYPE + tid) * 16;
            #pragma unroll
            for (int in = 0; in < 16; ++in) { bhist[base + in] = run; run += c[in]; }
            int slot0 = slab * SLAB_SLOTS + (excl >> 6);
            int nslots = padded >> 6;
            for (int q = 0; q < nslots; ++q) {
                int cq = sum - (q << 6);
                cq = cq > 64 ? 64 : cq;
                slotinfo[slot0 + q] = (cq << 8) | tid;
            }
            if (tid == 255) used = s[255] >> 6;
        }
        __syncthreads();
        for (int q = used + tid; q < SLAB_SLOTS; q += 1024)
            slotinfo[slab * SLAB_SLOTS + q] = 0;        // all-hole tail slots
    }
    grid.sync();

    // ---- P3: scatter element ids into padded sorted order ----
    {
        int slab = b & 15, inner = b >> 4;
        if (tid < NTYPE) lh[tid] = 0;
        __syncthreads();
        int e = slab * SLAB_EL + inner * 1024 + tid;
        int t = types[e];
        int rank = atomicAdd(&lh[t], 1);      // LDS-only atomic
        int pos = bhist[(slab * NTYPE + t) * 16 + inner] + rank;
        sorted[pos] = e;
    }
    grid.sync();

    // ---- P4: apply. Each block: 2048 entries of its slab's padded stream ----
    {
        int slab = (b & 7) + 8 * (b >> 7);
        int blk  = (b >> 3) & 15;             // 16 blocks per slab
        #pragma unroll
        for (int q = 0; q < 2; ++q) {
            int p = slab * SLAB_PAD + blk * 2048 + q * 1024 + tid;
            int slot = __builtin_amdgcn_readfirstlane(p >> 6);   // wave-uniform
            int packed = slotinfo[slot];                         // scalar load
            int t   = packed & 255;
            int cnt = packed >> 8;
            const float* __restrict__ F = filters + t * 576;     // SGPR base -> s_load
            if ((int)(tid & 63) < cnt) {
                int e = sorted[p];
                int k = e & 63, j = (e >> 6) & 63, i = (e >> 12) & 63;
                int i1 = (i + 1) & 63, j1 = (j + 1) & 63, k1 = (k + 1) & 63;
                int nodes[8];
                nodes[0] = IDX(i,  j,  k );
                nodes[1] = IDX(i1, j,  k );
                nodes[2] = IDX(i,  j1, k );
                nodes[3] = IDX(i1, j1, k );
                nodes[4] = IDX(i,  j,  k1);
                nodes[5] = IDX(i1, j,  k1);
                nodes[6] = IDX(i,  j1, k1);
                nodes[7] = IDX(i1, j1, k1);
                float Ue[24];
                #pragma unroll
                for (int m = 0; m < 8; ++m) {
                    float4 u = U4[nodes[m]];
                    Ue[3*m + 0] = u.x;
                    Ue[3*m + 1] = u.y;
                    Ue[3*m + 2] = u.z;
                }
                float o[24];
                #pragma unroll
                for (int r = 0; r < 24; ++r) {
                    float a = 0.0f;
                    #pragma unroll
                    for (int qq = 0; qq < 24; ++qq)
                        a = fmaf(F[r * 24 + qq], Ue[qq], a);   // SGPR filter operand
                    o[r] = a;
                }
                union { __half2 h[16]; float4 f[4]; } ob;
                #pragma unroll
                for (int c = 0; c < 8; ++c) {
                    ob.h[2*c + 0] = __floats2half2_rn(o[3*c + 0], o[3*c + 1]);
                    ob.h[2*c + 1] = __floats2half2_rn(o[3*c + 2], 0.0f);
                }
                float4* __restrict__ dst = KUe16 + (size_t)e * 4;   // 64 B line
                #pragma unroll
                for (int w = 0; w < 4; ++w) dst[w] = ob.f[w];
            }
        }
    }
    grid.sync();

    // ---- P5: reduce. One node per thread ----
    {
        int slab  = (b & 7) + 8 * (b >> 7);
        int inner = (b >> 3) & 15;
        int n = slab * SLAB_EL + inner * 1024 + tid;
        int k = n & 63, j = (n >> 6) & 63, i = (n >> 12) & 63;
        const int DI[8] = {0,1,0,1,0,1,0,1};
        const int DJ[8] = {0,0,1,1,0,0,1,1};
        const int DK[8] = {0,0,0,0,1,1,1,1};
        const uint2* __restrict__ KU2 = (const uint2*)KUe16;
        float a0 = 0.f, a1 = 0.f, a2 = 0.f;
        #pragma unroll
        for (int c = 0; c < 8; ++c) {
            int ei = (i - DI[c]) & 63;
            int ej = (j - DJ[c]) & 63;
            int ek = (k - DK[c]) & 63;
            uint2 v = KU2[(size_t)IDX(ei, ej, ek) * 8 + c];
            union { unsigned u; __half2 h; } ux, uy;
            ux.u = v.x; uy.u = v.y;
            a0 += __low2float(ux.h);
            a1 += __high2float(ux.h);
            a2 += __low2float(uy.h);
        }
        out[n*3 + 0] = a0;
        out[n*3 + 1] = a1;
        out[n*3 + 2] = a2;
    }
}

// ======================= round-9 fallback path =======================
__global__ __launch_bounds__(1024) void k1_hist(
    const float* __restrict__ U, const float* __restrict__ rho,
    float4* __restrict__ U4, unsigned char* __restrict__ types,
    int* __restrict__ bhist)
{
    __shared__ int lh[NTYPE];
    int tid = threadIdx.x;
    int b = blockIdx.x;
    int slab = b & 15, inner = b >> 4;
    if (tid < NTYPE) lh[tid] = 0;
    __syncthreads();
    int e = slab * SLAB_EL + inner * 1024 + tid;
    U4[e] = make_float4(U[3*e + 0], U[3*e + 1], U[3*e + 2], 0.0f);
    int k = e & 63, j = (e >> 6) & 63, i = (e >> 12) & 63;
    int t = type_of(rho, i, j, k);
    types[e] = (unsigned char)t;
    atomicAdd(&lh[t], 1);
    __syncthreads();
    if (tid < NTYPE) bhist[(slab * NTYPE + tid) * 16 + inner] = lh[tid];
}

__global__ __launch_bounds__(256) void k2_scan(
    int* __restrict__ bhist, int* __restrict__ slotinfo)
{
    int slab = blockIdx.x, t = threadIdx.x;
    int base = (slab * NTYPE + t) * 16;
    int c[16], sum = 0;
    #pragma unroll
    for (int in = 0; in < 16; ++in) { c[in] = bhist[base + in]; sum += c[in]; }
    int padded = (sum + 63) & ~63;
    __shared__ int s[256];
    __shared__ int used;
    s[t] = padded;
    __syncthreads();
    #pragma unroll
    for (int off = 1; off < 256; off <<= 1) {
        int tmp = (t >= off) ? s[t - off] : 0;
        __syncthreads();
        s[t] += tmp;
        __syncthreads();
    }
    int excl = s[t] - padded;
    int run = slab * SLAB_PAD + excl;
    #pragma unroll
    for (int in = 0; in < 16; ++in) { bhist[base + in] = run; run += c[in]; }
    int slot0 = slab * SLAB_SLOTS + (excl >> 6);
    int nslots = padded >> 6;
    for (int q = 0; q < nslots; ++q) {
        int cq = sum - (q << 6);
        cq = cq > 64 ? 64 : cq;
        slotinfo[slot0 + q] = (cq << 8) | t;
    }
    if (t == 255) used = s[255] >> 6;
    __syncthreads();
    for (int q = used + t; q < SLAB_SLOTS; q += 256)
        slotinfo[slab * SLAB_SLOTS + q] = 0;
}

__global__ __launch_bounds__(1024) void k3_scatter(
    const unsigned char* __restrict__ types, const int* __restrict__ bhist,
    int* __restrict__ sorted)
{
    __shared__ int lh[NTYPE];
    int tid = threadIdx.x;
    int b = blockIdx.x;
    int slab = b & 15, inner = b >> 4;
    if (tid < NTYPE) lh[tid] = 0;
    __syncthreads();
    int e = slab * SLAB_EL + inner * 1024 + tid;
    int t = types[e];
    int rank = atomicAdd(&lh[t], 1);
    int pos = bhist[(slab * NTYPE + t) * 16 + inner] + rank;
    sorted[pos] = e;
}

__global__ __launch_bounds__(256) void k4_apply(
    const float4* __restrict__ U4, const float* __restrict__ filters,
    const int* __restrict__ sorted, const int* __restrict__ slotinfo,
    float4* __restrict__ KUe16)
{
    int b = blockIdx.x;
    int hi = b >> 3;
    int slab = (b & 7) + 8 * (hi >> 7);
    int inner = hi & 127;
    int p = slab * SLAB_PAD + inner * 256 + threadIdx.x;
    int slot = __builtin_amdgcn_readfirstlane(p >> 6);
    int packed = slotinfo[slot];
    int t   = packed & 255;
    int cnt = packed >> 8;
    const float* __restrict__ F = filters + t * 576;
    if ((int)(threadIdx.x & 63) < cnt) {
        int e = sorted[p];
        int k = e & 63, j = (e >> 6) & 63, i = (e >> 12) & 63;
        int i1 = (i + 1) & 63, j1 = (j + 1) & 63, k1 = (k + 1) & 63;
        int nodes[8];
        nodes[0] = IDX(i,  j,  k );
        nodes[1] = IDX(i1, j,  k );
        nodes[2] = IDX(i,  j1, k );
        nodes[3] = IDX(i1, j1, k );
        nodes[4] = IDX(i,  j,  k1);
        nodes[5] = IDX(i1, j,  k1);
        nodes[6] = IDX(i,  j1, k1);
        nodes[7] = IDX(i1, j1, k1);
        float Ue[24];
        #pragma unroll
        for (int m = 0; m < 8; ++m) {
            float4 u = U4[nodes[m]];
            Ue[3*m + 0] = u.x;
            Ue[3*m + 1] = u.y;
            Ue[3*m + 2] = u.z;
        }
        float o[24];
        #pragma unroll
        for (int r = 0; r < 24; ++r) {
            float a = 0.0f;
            #pragma unroll
            for (int q = 0; q < 24; ++q)
                a = fmaf(F[r * 24 + q], Ue[q], a);
            o[r] = a;
        }
        union { __half2 h[16]; float4 f[4]; } ob;
        #pragma unroll
        for (int c = 0; c < 8; ++c) {
            ob.h[2*c + 0] = __floats2half2_rn(o[3*c + 0], o[3*c + 1]);
            ob.h[2*c + 1] = __floats2half2_rn(o[3*c + 2], 0.0f);
        }
        float4* __restrict__ dst = KUe16 + (size_t)e * 4;
        #pragma unroll
        for (int q = 0; q < 4; ++q) dst[q] = ob.f[q];
    }
}

__global__ __launch_bounds__(256) void k5_reduce(
    const uint2* __restrict__ KUe16, float* __restrict__ out)
{
    int b = blockIdx.x;
    int slab  = (b & 7) + 8 * (b >> 9);
    int chunk = (b >> 3) & 63;
    int n = slab * SLAB_EL + chunk * 256 + threadIdx.x;
    int k = n & 63, j = (n >> 6) & 63, i = (n >> 12) & 63;
    const int DI[8] = {0,1,0,1,0,1,0,1};
    const int DJ[8] = {0,0,1,1,0,0,1,1};
    const int DK[8] = {0,0,0,0,1,1,1,1};
    float a0 = 0.f, a1 = 0.f, a2 = 0.f;
    #pragma unroll
    for (int c = 0; c < 8; ++c) {
        int ei = (i - DI[c]) & 63;
        int ej = (j - DJ[c]) & 63;
        int ek = (k - DK[c]) & 63;
        uint2 v = KUe16[(size_t)IDX(ei, ej, ek) * 8 + c];
        union { unsigned u; __half2 h; } ux, uy;
        ux.u = v.x; uy.u = v.y;
        a0 += __low2float(ux.h);
        a1 += __high2float(ux.h);
        a2 += __low2float(uy.h);
    }
    out[n*3 + 0] = a0;
    out[n*3 + 1] = a1;
    out[n*3 + 2] = a2;
}

// Fallback (ws too small): round-1 atomic scatter kernel.
__global__ __launch_bounds__(256) void fe_apply_atomic(
    const float* __restrict__ U, const float* __restrict__ rho,
    const float* __restrict__ filters, float* __restrict__ out)
{
    int e = blockIdx.x * blockDim.x + threadIdx.x;
    int k = e & 63, j = (e >> 6) & 63, i = (e >> 12) & 63;
    int i1 = (i + 1) & 63, j1 = (j + 1) & 63, k1 = (k + 1) & 63;
    int nodes[8];
    nodes[0]=IDX(i,j,k);   nodes[1]=IDX(i1,j,k);   nodes[2]=IDX(i,j1,k);   nodes[3]=IDX(i1,j1,k);
    nodes[4]=IDX(i,j,k1);  nodes[5]=IDX(i1,j,k1);  nodes[6]=IDX(i,j1,k1);  nodes[7]=IDX(i1,j1,k1);
    int t = type_of(rho, i, j, k);
    float Ue[24];
    #pragma unroll
    for (int m = 0; m < 8; ++m) {
        int bb = nodes[m] * 3;
        Ue[3*m+0]=U[bb+0]; Ue[3*m+1]=U[bb+1]; Ue[3*m+2]=U[bb+2];
    }
    const float4* Kr = (const float4*)(filters + t * 576);
    #pragma unroll
    for (int r = 0; r < 24; ++r) {
        float a = 0.f;
        #pragma unroll
        for (int q = 0; q < 6; ++q) {
            float4 f = Kr[r*6+q];
            a = fmaf(f.x,Ue[4*q+0],a); a = fmaf(f.y,Ue[4*q+1],a);
            a = fmaf(f.z,Ue[4*q+2],a); a = fmaf(f.w,Ue[4*q+3],a);
        }
        atomicAdd(&out[nodes[r/3]*3 + (r%3)], a);
    }
}

extern "C" void kernel_launch(void* const* d_in, const int* in_sizes, int n_in,
                              void* d_out, int out_size, void* d_ws, size_t ws_size,
                              hipStream_t stream) {
    const float* U       = (const float*)d_in[0];
    const float* rho     = (const float*)d_in[1];
    const float* filters = (const float*)d_in[3];
    float* out = (float*)d_out;

    if (ws_size < WS_NEEDED) {
        hipMemsetAsync(out, 0, (size_t)out_size * sizeof(float), stream);
        fe_apply_atomic<<<dim3(NEL/256), dim3(256), 0, stream>>>(U, rho, filters, out);
        return;
    }

    char* ws = (char*)d_ws;
    float4*        U4       = (float4*)(ws + WS_U4);
    float4*        KUe16    = (float4*)(ws + WS_KUE);
    int*           sorted   = (int*)(ws + WS_SORTED);
    unsigned char* types    = (unsigned char*)(ws + WS_TYPES);
    int*           bhist    = (int*)(ws + WS_BHIST);
    int*           slotinfo = (int*)(ws + WS_SLOT);

    void* args[] = { (void*)&U, (void*)&rho, (void*)&filters,
                     (void*)&U4, (void*)&types, (void*)&bhist, (void*)&slotinfo,
                     (void*)&sorted, (void*)&KUe16, (void*)&out };
    hipError_t err = hipLaunchCooperativeKernel((const void*)fe_fused,
                                                dim3(256), dim3(1024),
                                                args, 0, stream);
    if (err != hipSuccess) {
        // fallback: proven round-9 5-kernel path
        k1_hist   <<<dim3(256),  dim3(1024), 0, stream>>>(U, rho, U4, types, bhist);
        k2_scan   <<<dim3(16),   dim3(256),  0, stream>>>(bhist, slotinfo);
        k3_scatter<<<dim3(256),  dim3(1024), 0, stream>>>(types, bhist, sorted);
        k4_apply  <<<dim3(2048), dim3(256),  0, stream>>>(U4, filters, sorted, slotinfo, KUe16);
        k5_reduce <<<dim3(1024), dim3(256),  0, stream>>>((const uint2*)KUe16, out);
    }
}

// Round 11
// 38.092 us; speedup vs baseline: 4.5159x; 4.5159x over previous
//
#include <hip/hip_runtime.h>
#include <hip/hip_fp16.h>

#define NGRID 64
#define NEL (NGRID*NGRID*NGRID)   /* 262144 */
#define IDX(i,j,k) ((((i)*64 + (j)) * 64) + (k))

#define NSLAB    16                /* slab = 4 consecutive i-planes = 16384 elements */
#define SLAB_EL  16384
#define NTYPE    256
#define SLAB_PAD 32768             /* per-slab sorted region (worst-case 64-padding) */
#define PADTOT   (NSLAB*SLAB_PAD)  /* 524288 */
#define NSLOT    (PADTOT/64)       /* 8192 slot-table entries */
#define SLAB_SLOTS (SLAB_PAD/64)   /* 512 */

#define STAGE_EL 2176              /* k5 staging: 2 i-planes x 17 j x 64 k */
#define K5_LDS   (8*STAGE_EL*8)    /* 139264 B, corner-major uint2 */

// ---- workspace layout (bytes) ----
#define WS_U4     0                                   // NEL float4 = 4 MB
#define WS_KUE    (WS_U4 + (size_t)NEL*16)            // NEL*64 B  = 16 MB (fp16, 1 line/elem)
#define WS_SORTED (WS_KUE + (size_t)NEL*64)           // PADTOT i32 = 2 MB
#define WS_TYPES  (WS_SORTED + (size_t)PADTOT*4)      // NEL u8 = 256 KB
#define WS_BHIST  (WS_TYPES + NEL)                    // 4096*16 i32 ([slab][type][inner16])
#define WS_SLOT   (WS_BHIST + 4096*16*4)              // NSLOT i32 = 32 KB
#define WS_NEEDED (size_t)(WS_SLOT + NSLOT*4)

__device__ __forceinline__ int type_of(const float* __restrict__ rho, int i, int j, int k) {
    int i1 = (i + 1) & 63, j1 = (j + 1) & 63, k1 = (k + 1) & 63;
    // typeFilter[di][dj][dk] = 2^(di*4 + dj*2 + dk); OFFSETS order -> bits {0,4,2,6,1,5,3,7}
    int t = 0;
    t |= (rho[IDX(i,  j,  k )] > 0.5f ? 1 : 0) << 0;
    t |= (rho[IDX(i1, j,  k )] > 0.5f ? 1 : 0) << 4;
    t |= (rho[IDX(i,  j1, k )] > 0.5f ? 1 : 0) << 2;
    t |= (rho[IDX(i1, j1, k )] > 0.5f ? 1 : 0) << 6;
    t |= (rho[IDX(i,  j,  k1)] > 0.5f ? 1 : 0) << 1;
    t |= (rho[IDX(i1, j,  k1)] > 0.5f ? 1 : 0) << 5;
    t |= (rho[IDX(i,  j1, k1)] > 0.5f ? 1 : 0) << 3;
    t |= (rho[IDX(i1, j1, k1)] > 0.5f ? 1 : 0) << 7;
    return t;
}

// K1: 256 blocks x 1024 thr; slab = b&15, inner = b>>4.
// Pack U->float4, types, per-(slab,type,inner) LDS histogram. No global atomics.
__global__ __launch_bounds__(1024) void k1_hist(
    const float* __restrict__ U, const float* __restrict__ rho,
    float4* __restrict__ U4, unsigned char* __restrict__ types,
    int* __restrict__ bhist)
{
    __shared__ int lh[NTYPE];
    int tid = threadIdx.x;
    int b = blockIdx.x;
    int slab = b & 15, inner = b >> 4;
    if (tid < NTYPE) lh[tid] = 0;
    __syncthreads();
    int e = slab * SLAB_EL + inner * 1024 + tid;
    U4[e] = make_float4(U[3*e + 0], U[3*e + 1], U[3*e + 2], 0.0f);
    int k = e & 63, j = (e >> 6) & 63, i = (e >> 12) & 63;
    int t = type_of(rho, i, j, k);
    types[e] = (unsigned char)t;
    atomicAdd(&lh[t], 1);                 // LDS-only atomic
    __syncthreads();
    if (tid < NTYPE) bhist[(slab * NTYPE + tid) * 16 + inner] = lh[tid];
}

// K3 (merged old k2+k3): each block redundantly loads its slab's histogram
// (16 KB from L2), scans padded bucket sizes in LDS, derives its own write
// bases, and scatters. inner==0 blocks also emit the slot table.
__global__ __launch_bounds__(1024) void k3_scan_scatter(
    const unsigned char* __restrict__ types, const int* __restrict__ bhist,
    int* __restrict__ sorted, int* __restrict__ slotinfo)
{
    __shared__ int s[NTYPE];     // padded-size scan
    __shared__ int off[NTYPE];   // this block's write base per type
    __shared__ int lh[NTYPE];    // ranks
    __shared__ int used;
    int tid = threadIdx.x;
    int b = blockIdx.x;
    int slab = b & 15, inner = b >> 4;

    int c[16], sum = 0, before = 0, padded = 0;
    if (tid < NTYPE) {
        lh[tid] = 0;
        int base = (slab * NTYPE + tid) * 16;
        #pragma unroll
        for (int in = 0; in < 16; ++in) {
            c[in] = bhist[base + in];
            if (in < inner) before += c[in];
            sum += c[in];
        }
        padded = (sum + 63) & ~63;
        s[tid] = padded;
    }
    __syncthreads();
    #pragma unroll
    for (int o = 1; o < NTYPE; o <<= 1) {
        int tmp = (tid < NTYPE && tid >= o) ? s[tid - o] : 0;
        __syncthreads();
        if (tid < NTYPE) s[tid] += tmp;
        __syncthreads();
    }
    if (tid < NTYPE) {
        int excl = s[tid] - padded;              // exclusive scan (mult of 64)
        off[tid] = slab * SLAB_PAD + excl + before;
        if (inner == 0) {
            int slot0 = slab * SLAB_SLOTS + (excl >> 6);
            int nslots = padded >> 6;
            for (int q = 0; q < nslots; ++q) {
                int cq = sum - (q << 6);
                cq = cq > 64 ? 64 : cq;
                slotinfo[slot0 + q] = (cq << 8) | tid;
            }
            if (tid == 255) used = s[255] >> 6;
        }
    }
    __syncthreads();
    if (inner == 0) {
        for (int q = used + tid; q < SLAB_SLOTS; q += 1024)
            slotinfo[slab * SLAB_SLOTS + q] = 0;  // all-hole tail slots
    }
    int e = slab * SLAB_EL + inner * 1024 + tid;
    int t = types[e];
    int rank = atomicAdd(&lh[t], 1);              // LDS-only atomic
    sorted[off[t] + rank] = e;
}

// K4: 2048 blocks x 256 thr over the padded sorted stream. Wave-uniform slot
// entry (s_load) gives scalar type+count; SGPR filter; 8 float4 U4 gathers;
// 24x24 matvec; one full 64 B fp16 line per element.
__global__ __launch_bounds__(256) void k4_apply(
    const float4* __restrict__ U4, const float* __restrict__ filters,
    const int* __restrict__ sorted, const int* __restrict__ slotinfo,
    float4* __restrict__ KUe16)
{
    int b = blockIdx.x;
    int hi = b >> 3;
    int slab = (b & 7) + 8 * (hi >> 7);
    int inner = hi & 127;
    int p = slab * SLAB_PAD + inner * 256 + threadIdx.x;

    int slot = __builtin_amdgcn_readfirstlane(p >> 6);   // wave-uniform
    int packed = slotinfo[slot];                         // scalar load
    int t   = packed & 255;
    int cnt = packed >> 8;
    const float* __restrict__ F = filters + t * 576;     // SGPR base -> s_load

    if ((int)(threadIdx.x & 63) < cnt) {
        int e = sorted[p];
        int k = e & 63, j = (e >> 6) & 63, i = (e >> 12) & 63;
        int i1 = (i + 1) & 63, j1 = (j + 1) & 63, k1 = (k + 1) & 63;
        int nodes[8];
        nodes[0] = IDX(i,  j,  k );
        nodes[1] = IDX(i1, j,  k );
        nodes[2] = IDX(i,  j1, k );
        nodes[3] = IDX(i1, j1, k );
        nodes[4] = IDX(i,  j,  k1);
        nodes[5] = IDX(i1, j,  k1);
        nodes[6] = IDX(i,  j1, k1);
        nodes[7] = IDX(i1, j1, k1);
        float Ue[24];
        #pragma unroll
        for (int m = 0; m < 8; ++m) {
            float4 u = U4[nodes[m]];
            Ue[3*m + 0] = u.x;
            Ue[3*m + 1] = u.y;
            Ue[3*m + 2] = u.z;
        }
        float o[24];
        #pragma unroll
        for (int r = 0; r < 24; ++r) {
            float a = 0.0f;
            #pragma unroll
            for (int q = 0; q < 24; ++q)
                a = fmaf(F[r * 24 + q], Ue[q], a);   // SGPR filter operand
            o[r] = a;
        }
        union { __half2 h[16]; float4 f[4]; } ob;
        #pragma unroll
        for (int c = 0; c < 8; ++c) {
            ob.h[2*c + 0] = __floats2half2_rn(o[3*c + 0], o[3*c + 1]);
            ob.h[2*c + 1] = __floats2half2_rn(o[3*c + 2], 0.0f);
        }
        float4* __restrict__ dst = KUe16 + (size_t)e * 4;   // 64 B line
        #pragma unroll
        for (int q = 0; q < 4; ++q) dst[q] = ob.f[q];
    }
}

// K5: LDS-staged reduce. Block = 1024 nodes (one i-plane quarter: fixed i,
// 16 j-rows, all k). Stage the 2x17x64 needed elements' KUe lines with
// coalesced dwordx4 streams into corner-major LDS, then 8 conflict-free
// ds_read_b64 per node. One coalesced-ish 12 B store per node.
__global__ __launch_bounds__(1024) void k5_reduce(
    const uint4* __restrict__ KUe4, float* __restrict__ out)
{
    extern __shared__ uint2 cache[];   // [8][STAGE_EL] corner-major
    int tid = threadIdx.x;
    int b = blockIdx.x;
    int slab  = (b & 7) + 8 * (b >> 7);
    int inner = (b >> 3) & 15;
    int i  = slab * 4 + (inner >> 2);
    int j0 = (inner & 3) << 4;
    int im1 = (i - 1) & 63;

    // stage: 2176 elements x 4 dwordx4 each
    for (int f = tid; f < STAGE_EL * 4; f += 1024) {
        int le = f >> 2, s = f & 3;
        int pi = (le >= 1088) ? 1 : 0;
        int rem = le - pi * 1088;
        int pj = rem >> 6, ek = rem & 63;
        int ei = pi ? i : im1;
        int ej = (j0 - 1 + pj) & 63;
        uint4 v = KUe4[(size_t)IDX(ei, ej, ek) * 4 + s];
        cache[(2*s)     * STAGE_EL + le] = make_uint2(v.x, v.y);
        cache[(2*s + 1) * STAGE_EL + le] = make_uint2(v.z, v.w);
    }
    __syncthreads();

    int jj = tid >> 6, k = tid & 63;
    int n = IDX(i, j0 + jj, k);
    const int DI[8] = {0,1,0,1,0,1,0,1};
    const int DJ[8] = {0,0,1,1,0,0,1,1};
    const int DK[8] = {0,0,0,0,1,1,1,1};
    float a0 = 0.f, a1 = 0.f, a2 = 0.f;
    #pragma unroll
    for (int c = 0; c < 8; ++c) {
        int pi = 1 - DI[c];
        int pj = jj + 1 - DJ[c];
        int ek = (k - DK[c]) & 63;
        uint2 v = cache[c * STAGE_EL + pi * 1088 + pj * 64 + ek];
        union { unsigned u; __half2 h; } ux, uy;
        ux.u = v.x; uy.u = v.y;
        a0 += __low2float(ux.h);
        a1 += __high2float(ux.h);
        a2 += __low2float(uy.h);
    }
    out[n*3 + 0] = a0;
    out[n*3 + 1] = a1;
    out[n*3 + 2] = a2;
}

// Fallback (ws too small): round-1 atomic scatter kernel.
__global__ __launch_bounds__(256) void fe_apply_atomic(
    const float* __restrict__ U, const float* __restrict__ rho,
    const float* __restrict__ filters, float* __restrict__ out)
{
    int e = blockIdx.x * blockDim.x + threadIdx.x;
    int k = e & 63, j = (e >> 6) & 63, i = (e >> 12) & 63;
    int i1 = (i + 1) & 63, j1 = (j + 1) & 63, k1 = (k + 1) & 63;
    int nodes[8];
    nodes[0]=IDX(i,j,k);   nodes[1]=IDX(i1,j,k);   nodes[2]=IDX(i,j1,k);   nodes[3]=IDX(i1,j1,k);
    nodes[4]=IDX(i,j,k1);  nodes[5]=IDX(i1,j,k1);  nodes[6]=IDX(i,j1,k1);  nodes[7]=IDX(i1,j1,k1);
    int t = type_of(rho, i, j, k);
    float Ue[24];
    #pragma unroll
    for (int m = 0; m < 8; ++m) {
        int bb = nodes[m] * 3;
        Ue[3*m+0]=U[bb+0]; Ue[3*m+1]=U[bb+1]; Ue[3*m+2]=U[bb+2];
    }
    const float4* Kr = (const float4*)(filters + t * 576);
    #pragma unroll
    for (int r = 0; r < 24; ++r) {
        float a = 0.f;
        #pragma unroll
        for (int q = 0; q < 6; ++q) {
            float4 f = Kr[r*6+q];
            a = fmaf(f.x,Ue[4*q+0],a); a = fmaf(f.y,Ue[4*q+1],a);
            a = fmaf(f.z,Ue[4*q+2],a); a = fmaf(f.w,Ue[4*q+3],a);
        }
        atomicAdd(&out[nodes[r/3]*3 + (r%3)], a);
    }
}

extern "C" void kernel_launch(void* const* d_in, const int* in_sizes, int n_in,
                              void* d_out, int out_size, void* d_ws, size_t ws_size,
                              hipStream_t stream) {
    const float* U       = (const float*)d_in[0];
    const float* rho     = (const float*)d_in[1];
    const float* filters = (const float*)d_in[3];
    float* out = (float*)d_out;

    if (ws_size < WS_NEEDED) {
        hipMemsetAsync(out, 0, (size_t)out_size * sizeof(float), stream);
        fe_apply_atomic<<<dim3(NEL/256), dim3(256), 0, stream>>>(U, rho, filters, out);
        return;
    }

    char* ws = (char*)d_ws;
    float4*        U4       = (float4*)(ws + WS_U4);
    float4*        KUe16    = (float4*)(ws + WS_KUE);
    int*           sorted   = (int*)(ws + WS_SORTED);
    unsigned char* types    = (unsigned char*)(ws + WS_TYPES);
    int*           bhist    = (int*)(ws + WS_BHIST);
    int*           slotinfo = (int*)(ws + WS_SLOT);

    // allow 139 KB dynamic LDS for k5 (idempotent; not a stream op)
    (void)hipFuncSetAttribute((const void*)k5_reduce,
                              hipFuncAttributeMaxDynamicSharedMemorySize, K5_LDS);

    k1_hist        <<<dim3(256),  dim3(1024), 0,      stream>>>(U, rho, U4, types, bhist);
    k3_scan_scatter<<<dim3(256),  dim3(1024), 0,      stream>>>(types, bhist, sorted, slotinfo);
    k4_apply       <<<dim3(2048), dim3(256),  0,      stream>>>(U4, filters, sorted, slotinfo, KUe16);
    k5_reduce      <<<dim3(256),  dim3(1024), K5_LDS, stream>>>((const uint4*)KUe16, out);
}